// Round 12
// baseline (65.959 us; speedup 1.0000x reference)
//
#include <hip/hip_runtime.h>

// Problem dims (fixed by reference)
#define BB   2
#define NBB  32
#define PP   128
#define FF   32
#define HH   32
#define NO   8
#define OUTC 32
#define NROWS (BB*NBB*PP)   // 8192

typedef float    f32x4 __attribute__((ext_vector_type(4)));
typedef _Float16 f16x8 __attribute__((ext_vector_type(8)));
typedef _Float16 f16x4 __attribute__((ext_vector_type(4)));
typedef _Float16 f16x2 __attribute__((ext_vector_type(2)));

__device__ __forceinline__ float elu_f(float x){
    return x > 0.0f ? x : (__expf(x) - 1.0f);
}
// packed fp32x2 -> fp16x2 (RTZ), bit-cast to _Float16 vector type
__device__ __forceinline__ f16x2 pk16(float a, float b){
    return __builtin_bit_cast(f16x2, __builtin_amdgcn_cvt_pkrtz(a, b));
}

// Kernel A: node MLP + projection to pa/pb (pair_b0 folded into pa).
__global__ __launch_bounds__(256) void node_kernel(
    const float* __restrict__ x,  const float* __restrict__ msk,
    const float* __restrict__ w0, const float* __restrict__ b0,
    const float* __restrict__ w1, const float* __restrict__ b1,
    const float* __restrict__ w2, const float* __restrict__ b2,
    const float* __restrict__ pw0,const float* __restrict__ pb0,
    float* __restrict__ pa, float* __restrict__ pb)
{
    int row = blockIdx.x*256 + threadIdx.x;
    if (row >= NROWS) return;

    float xr[FF];
    const float4* xp = reinterpret_cast<const float4*>(x + (size_t)row*FF);
#pragma unroll
    for (int q=0;q<FF/4;q++){ float4 v=xp[q]; xr[4*q]=v.x; xr[4*q+1]=v.y; xr[4*q+2]=v.z; xr[4*q+3]=v.w; }

    float h[HH];
#pragma unroll
    for (int k=0;k<HH;k++) h[k]=b0[k];
#pragma unroll
    for (int m=0;m<FF;m++){
        float xm = xr[m];
#pragma unroll
        for (int k=0;k<HH;k++) h[k] += xm * w0[m*HH+k];
    }
#pragma unroll
    for (int k=0;k<HH;k++) h[k]=elu_f(h[k]);

    float g[HH];
#pragma unroll
    for (int k=0;k<HH;k++) g[k]=b1[k];
#pragma unroll
    for (int m=0;m<HH;m++){
        float hm=h[m];
#pragma unroll
        for (int k=0;k<HH;k++) g[k] += hm * w1[m*HH+k];
    }
#pragma unroll
    for (int k=0;k<HH;k++) g[k]=elu_f(g[k]);

    float mk = msk[row];
    float npj[NO];
#pragma unroll
    for (int k=0;k<NO;k++) npj[k]=b2[k];
#pragma unroll
    for (int m=0;m<HH;m++){
        float gm=g[m];
#pragma unroll
        for (int k=0;k<NO;k++) npj[k] += gm * w2[m*NO+k];
    }
#pragma unroll
    for (int k=0;k<NO;k++) npj[k]=elu_f(npj[k])*mk;

    float pav[HH], pbv[HH];
#pragma unroll
    for (int k=0;k<HH;k++){ pav[k]=pb0[k]; pbv[k]=0.0f; }
#pragma unroll
    for (int m=0;m<NO;m++){
        float nm=npj[m];
#pragma unroll
        for (int k=0;k<HH;k++){
            pav[k] += nm * pw0[m*HH+k];
            pbv[k] += nm * pw0[(NO+m)*HH+k];
        }
    }
    float4* pap = reinterpret_cast<float4*>(pa + (size_t)row*HH);
    float4* pbp = reinterpret_cast<float4*>(pb + (size_t)row*HH);
#pragma unroll
    for (int q=0;q<HH/4;q++){
        pap[q]=make_float4(pav[4*q],pav[4*q+1],pav[4*q+2],pav[4*q+3]);
        pbp[q]=make_float4(pbv[4*q],pbv[4*q+1],pbv[4*q+2],pbv[4*q+3]);
    }
}

// ---- Transposed-MFMA pair kernel, fp16, ZERO-LDS layer handoff ----
// H1^T = W1^T @ H0^T via mfma_f32_16x16x32_f16:
//   A frag: row m=ln(+16mt), k=8h+{0..7};  B frag: col=pair ln(+16jj), k=8h+{0..7}
//   D frag: col=pair ln, row m=feat 16mt+4h+{0..3}
// KEY (R11->R12): the L1 D fragment IS the B fragment of
// mfma_f32_16x16x16_f16 (lane (ln,h): col=ln, k=4h+{0..3}), with mt as the
// K=16 chain index. So layer 2 (O^T = W2^T @ H1^T) consumes layer 1's
// accumulator DIRECTLY in registers: two chained 16x16x16 MFMAs replace the
// ds_write/lgkmcnt/ds_read h1 round-trip that sat on every iteration's
// critical path. Loop LDS traffic = pas reads only (read-only -> freely
// reorderable across i). LDS 21.5 KB -> 1 KB.
//   16x16x16 A frag: row m=ln(+16mtO), k=4h+{0..3}(+16kc)  [gfx908 layout]
// Direct D-frag stores unchanged (16 rows x 64 B full sectors, mt halves
// back-to-back; proven clean R8->R9).
#define SM_SIZE 1024     // pas: 8 rows * 32 f32

__global__ __launch_bounds__(256, 4) void pair_kernel(
    const float* __restrict__ pa, const float* __restrict__ pb,
    const float* __restrict__ pw1, const float* __restrict__ pb1,
    const float* __restrict__ pw2, const float* __restrict__ pb2,
    float* __restrict__ out)
{
    __shared__ __align__(16) float pas[SM_SIZE/4];

    const int t   = threadIdx.x;
    const int l   = t & 63;
    const int w   = t >> 6;
    const int h   = l >> 4;
    const int ln  = l & 15;
    const int bnb = blockIdx.x >> 4;
    const int ic  = blockIdx.x & 15;

    // ---- stage pa rows for this block's 8 i's (pair_b0 folded)
    if (t < 64)
        ((f32x4*)pas)[t] = ((const f32x4*)(pa + ((size_t)bnb*PP + ic*8)*HH))[t];

    // ---- Layer-1 W1^T A-fragments (16x16x32: k=8h+{0..7})
    f16x8 wfr1[2];   // [mt]
#pragma unroll
    for (int mt=0; mt<2; mt++){
        f16x8 a;
#pragma unroll
        for (int e=0; e<8; e++)
            a[e] = (_Float16)pw1[(8*h+e)*32 + 16*mt + ln];   // W1^T[m][k]=W1[k][m]
        wfr1[mt] = a;
    }
    // ---- Layer-2 W2^T A-fragments (16x16x16: k=4h+{0..3}, chained kc)
    f16x4 w2t[2][2]; // [mtO][kc]
#pragma unroll
    for (int mtO=0; mtO<2; mtO++)
#pragma unroll
    for (int kc=0; kc<2; kc++){
        f16x4 a;
#pragma unroll
        for (int e=0; e<4; e++)
            a[e] = (_Float16)pw2[(16*kc + 4*h + e)*32 + 16*mtO + ln];
        w2t[mtO][kc] = a;
    }

    // ---- biases as D-fragment f32x4 (feature = 16mt+4h+q)
    f32x4 b1v[2], b2v[2];
#pragma unroll
    for (int mt=0; mt<2; mt++){
        b1v[mt] = *(const f32x4*)(pb1 + 16*mt + 4*h);
        b2v[mt] = *(const f32x4*)(pb2 + 16*mt + 4*h);
    }

    // ---- pb slices (lane's B-frag k-slice for its 2 pair-tiles), hoisted
    float pbr[2][8];
#pragma unroll
    for (int jj=0; jj<2; jj++){
        const float* q = pb + ((size_t)bnb*PP + 32*w + 16*jj + ln)*HH + 8*h;
        f32x4 v0 = *(const f32x4*)q, v1 = *(const f32x4*)(q+4);
#pragma unroll
        for (int c=0;c<4;c++){ pbr[jj][c]=v0[c]; pbr[jj][4+c]=v1[c]; }
    }
    __syncthreads();   // pas visible to all

#pragma unroll 2
    for (int i = 0; i < 8; i++){
        // ---- H0^T B-fragments straight into registers (fp16, packed cvt)
        float par[8];
        {
            const f32x4* pp = (const f32x4*)(pas + i*32 + 8*h);
            f32x4 v0 = pp[0], v1 = pp[1];
#pragma unroll
            for (int c=0;c<4;c++){ par[c]=v0[c]; par[4+c]=v1[c]; }
        }
        f16x8 bh[2];
#pragma unroll
        for (int jj=0; jj<2; jj++){
            float e0[8];
#pragma unroll
            for (int e=0; e<8; e++) e0[e] = elu_f(par[e] + pbr[jj][e]);
            f16x2 p0 = pk16(e0[0], e0[1]);
            f16x2 p1 = pk16(e0[2], e0[3]);
            f16x2 p2 = pk16(e0[4], e0[5]);
            f16x2 p3 = pk16(e0[6], e0[7]);
            f16x8 b = {p0[0],p0[1],p1[0],p1[1],p2[0],p2[1],p3[0],p3[1]};
            bh[jj] = b;
        }

        // ---- Layer 1: H1^T = W1^T @ H0^T (K=32)
        f32x4 acc[2][2];   // [mt=feat-tile][jj]
#pragma unroll
        for (int mt=0; mt<2; mt++)
#pragma unroll
        for (int jj=0; jj<2; jj++)
            acc[mt][jj] = __builtin_amdgcn_mfma_f32_16x16x32_f16(
                              wfr1[mt], bh[jj], b1v[mt], 0,0,0);

        // ---- elu + cvt: acc IS the 16x16x16 B-fragment (kc = mt)
        f16x4 bf[2][2];    // [jj][kc]
#pragma unroll
        for (int jj=0; jj<2; jj++)
#pragma unroll
        for (int kc=0; kc<2; kc++){
            f16x2 q0 = pk16(elu_f(acc[kc][jj][0]), elu_f(acc[kc][jj][1]));
            f16x2 q1 = pk16(elu_f(acc[kc][jj][2]), elu_f(acc[kc][jj][3]));
            f16x4 p = {q0[0],q0[1],q1[0],q1[1]};
            bf[jj][kc] = p;
        }

        // ---- Layer 2: O^T = W2^T @ H1^T (2 chained K=16 MFMAs) + store
        float* obase = out + ((size_t)(bnb*PP + ic*8 + i))*PP*OUTC;
#pragma unroll
        for (int jj=0; jj<2; jj++){
            int j = 32*w + 16*jj + ln;
#pragma unroll
            for (int mtO=0; mtO<2; mtO++){
                f32x4 c = b2v[mtO];
                c = __builtin_amdgcn_mfma_f32_16x16x16f16(w2t[mtO][0], bf[jj][0], c, 0,0,0);
                c = __builtin_amdgcn_mfma_f32_16x16x16f16(w2t[mtO][1], bf[jj][1], c, 0,0,0);
                f32x4 o;
#pragma unroll
                for (int q=0; q<4; q++) o[q] = elu_f(c[q]);
                *(f32x4*)(obase + (size_t)j*OUTC + 16*mtO + 4*h) = o;
            }
        }
        // no barrier, no loop LDS writes: stores drain asynchronously.
    }
}

extern "C" void kernel_launch(void* const* d_in, const int* in_sizes, int n_in,
                              void* d_out, int out_size, void* d_ws, size_t ws_size,
                              hipStream_t stream) {
    const float* x    = (const float*)d_in[0];
    const float* msk  = (const float*)d_in[1];
    const float* nw0  = (const float*)d_in[2];
    const float* nb0  = (const float*)d_in[3];
    const float* nw1  = (const float*)d_in[4];
    const float* nb1  = (const float*)d_in[5];
    const float* nw2  = (const float*)d_in[6];
    const float* nb2  = (const float*)d_in[7];
    const float* pw0  = (const float*)d_in[8];
    const float* pb0  = (const float*)d_in[9];
    const float* pw1  = (const float*)d_in[10];
    const float* pb1  = (const float*)d_in[11];
    const float* pw2  = (const float*)d_in[12];
    const float* pb2  = (const float*)d_in[13];
    float* out = (float*)d_out;

    float* pa = (float*)d_ws;                       // 8192*32 floats = 1 MiB
    float* pb = pa + (size_t)NROWS*HH;              // +1 MiB

    node_kernel<<<NROWS/256, 256, 0, stream>>>(x, msk, nw0, nb0, nw1, nb1,
                                               nw2, nb2, pw0, pb0, pa, pb);
    pair_kernel<<<BB*NBB*16, 256, 0, stream>>>(pa, pb, pw1, pb1,
                                               pw2, pb2, out);
}

// Round 13
// 65.756 us; speedup vs baseline: 1.0031x; 1.0031x over previous
//
#include <hip/hip_runtime.h>

// Problem dims (fixed by reference)
#define BB   2
#define NBB  32
#define PP   128
#define FF   32
#define HH   32
#define NO   8
#define OUTC 32
#define NROWS (BB*NBB*PP)   // 8192

typedef float    f32x4 __attribute__((ext_vector_type(4)));
typedef _Float16 f16x8 __attribute__((ext_vector_type(8)));
typedef _Float16 f16x4 __attribute__((ext_vector_type(4)));
typedef _Float16 f16x2 __attribute__((ext_vector_type(2)));

__device__ __forceinline__ float elu_f(float x){
    return x > 0.0f ? x : (__expf(x) - 1.0f);
}
// packed fp32x2 -> fp16x2 (RTZ), bit-cast to _Float16 vector type
__device__ __forceinline__ f16x2 pk16(float a, float b){
    return __builtin_bit_cast(f16x2, __builtin_amdgcn_cvt_pkrtz(a, b));
}

// Kernel A: node MLP + projection to pa/pb (pair_b0 folded into pa).
__global__ __launch_bounds__(256) void node_kernel(
    const float* __restrict__ x,  const float* __restrict__ msk,
    const float* __restrict__ w0, const float* __restrict__ b0,
    const float* __restrict__ w1, const float* __restrict__ b1,
    const float* __restrict__ w2, const float* __restrict__ b2,
    const float* __restrict__ pw0,const float* __restrict__ pb0,
    float* __restrict__ pa, float* __restrict__ pb)
{
    int row = blockIdx.x*256 + threadIdx.x;
    if (row >= NROWS) return;

    float xr[FF];
    const float4* xp = reinterpret_cast<const float4*>(x + (size_t)row*FF);
#pragma unroll
    for (int q=0;q<FF/4;q++){ float4 v=xp[q]; xr[4*q]=v.x; xr[4*q+1]=v.y; xr[4*q+2]=v.z; xr[4*q+3]=v.w; }

    float h[HH];
#pragma unroll
    for (int k=0;k<HH;k++) h[k]=b0[k];
#pragma unroll
    for (int m=0;m<FF;m++){
        float xm = xr[m];
#pragma unroll
        for (int k=0;k<HH;k++) h[k] += xm * w0[m*HH+k];
    }
#pragma unroll
    for (int k=0;k<HH;k++) h[k]=elu_f(h[k]);

    float g[HH];
#pragma unroll
    for (int k=0;k<HH;k++) g[k]=b1[k];
#pragma unroll
    for (int m=0;m<HH;m++){
        float hm=h[m];
#pragma unroll
        for (int k=0;k<HH;k++) g[k] += hm * w1[m*HH+k];
    }
#pragma unroll
    for (int k=0;k<HH;k++) g[k]=elu_f(g[k]);

    float mk = msk[row];
    float npj[NO];
#pragma unroll
    for (int k=0;k<NO;k++) npj[k]=b2[k];
#pragma unroll
    for (int m=0;m<HH;m++){
        float gm=g[m];
#pragma unroll
        for (int k=0;k<NO;k++) npj[k] += gm * w2[m*NO+k];
    }
#pragma unroll
    for (int k=0;k<NO;k++) npj[k]=elu_f(npj[k])*mk;

    float pav[HH], pbv[HH];
#pragma unroll
    for (int k=0;k<HH;k++){ pav[k]=pb0[k]; pbv[k]=0.0f; }
#pragma unroll
    for (int m=0;m<NO;m++){
        float nm=npj[m];
#pragma unroll
        for (int k=0;k<HH;k++){
            pav[k] += nm * pw0[m*HH+k];
            pbv[k] += nm * pw0[(NO+m)*HH+k];
        }
    }
    float4* pap = reinterpret_cast<float4*>(pa + (size_t)row*HH);
    float4* pbp = reinterpret_cast<float4*>(pb + (size_t)row*HH);
#pragma unroll
    for (int q=0;q<HH/4;q++){
        pap[q]=make_float4(pav[4*q],pav[4*q+1],pav[4*q+2],pav[4*q+3]);
        pbp[q]=make_float4(pbv[4*q],pbv[4*q+1],pbv[4*q+2],pbv[4*q+3]);
    }
}

// ---- Transposed-MFMA pair kernel, fp16, ZERO-LDS layer handoff ----
// H1^T = W1^T @ H0^T via mfma_f32_16x16x32_f16:
//   A frag: row m=ln(+16mt), k=8h+{0..7};  B frag: col=pair ln(+16jj), k=8h+{0..7}
//   D frag: col=pair ln, row m=feat 16mt+4h+{0..3}
// L1 D fragment consumed directly as the 16x16x16 B fragment (kc = mt chain).
// R12->R13 single change: __launch_bounds__(256,4) -> (256,2).
// The 128-VGPR cap that (256,4) imposed is ~2 registers short of holding two
// iterations' live state (wfr1 8 + w2t 8 + biases 16 + pbr 16 + 2x{par 8,
// bh 8, acc 16, bf 8} + addressing ~ 130+), so the allocator serialized the
// unroll-2 iterations -- explaining why R11's double-buffer and R12's
// zero-LDS handoff both nulled at the same 66 us: cross-iteration ILP was
// register-starved, not memory-blocked. (256,2) lets VGPR grow to ~160,
// trading 4 -> 3 waves/SIMD for genuine cross-i overlap.
#define SM_SIZE 1024     // pas: 8 rows * 32 f32

__global__ __launch_bounds__(256, 2) void pair_kernel(
    const float* __restrict__ pa, const float* __restrict__ pb,
    const float* __restrict__ pw1, const float* __restrict__ pb1,
    const float* __restrict__ pw2, const float* __restrict__ pb2,
    float* __restrict__ out)
{
    __shared__ __align__(16) float pas[SM_SIZE/4];

    const int t   = threadIdx.x;
    const int l   = t & 63;
    const int w   = t >> 6;
    const int h   = l >> 4;
    const int ln  = l & 15;
    const int bnb = blockIdx.x >> 4;
    const int ic  = blockIdx.x & 15;

    // ---- stage pa rows for this block's 8 i's (pair_b0 folded)
    if (t < 64)
        ((f32x4*)pas)[t] = ((const f32x4*)(pa + ((size_t)bnb*PP + ic*8)*HH))[t];

    // ---- Layer-1 W1^T A-fragments (16x16x32: k=8h+{0..7})
    f16x8 wfr1[2];   // [mt]
#pragma unroll
    for (int mt=0; mt<2; mt++){
        f16x8 a;
#pragma unroll
        for (int e=0; e<8; e++)
            a[e] = (_Float16)pw1[(8*h+e)*32 + 16*mt + ln];   // W1^T[m][k]=W1[k][m]
        wfr1[mt] = a;
    }
    // ---- Layer-2 W2^T A-fragments (16x16x16: k=4h+{0..3}, chained kc)
    f16x4 w2t[2][2]; // [mtO][kc]
#pragma unroll
    for (int mtO=0; mtO<2; mtO++)
#pragma unroll
    for (int kc=0; kc<2; kc++){
        f16x4 a;
#pragma unroll
        for (int e=0; e<4; e++)
            a[e] = (_Float16)pw2[(16*kc + 4*h + e)*32 + 16*mtO + ln];
        w2t[mtO][kc] = a;
    }

    // ---- biases as D-fragment f32x4 (feature = 16mt+4h+q)
    f32x4 b1v[2], b2v[2];
#pragma unroll
    for (int mt=0; mt<2; mt++){
        b1v[mt] = *(const f32x4*)(pb1 + 16*mt + 4*h);
        b2v[mt] = *(const f32x4*)(pb2 + 16*mt + 4*h);
    }

    // ---- pb slices (lane's B-frag k-slice for its 2 pair-tiles), hoisted
    float pbr[2][8];
#pragma unroll
    for (int jj=0; jj<2; jj++){
        const float* q = pb + ((size_t)bnb*PP + 32*w + 16*jj + ln)*HH + 8*h;
        f32x4 v0 = *(const f32x4*)q, v1 = *(const f32x4*)(q+4);
#pragma unroll
        for (int c=0;c<4;c++){ pbr[jj][c]=v0[c]; pbr[jj][4+c]=v1[c]; }
    }
    __syncthreads();   // pas visible to all

#pragma unroll 2
    for (int i = 0; i < 8; i++){
        // ---- H0^T B-fragments straight into registers (fp16, packed cvt)
        float par[8];
        {
            const f32x4* pp = (const f32x4*)(pas + i*32 + 8*h);
            f32x4 v0 = pp[0], v1 = pp[1];
#pragma unroll
            for (int c=0;c<4;c++){ par[c]=v0[c]; par[4+c]=v1[c]; }
        }
        f16x8 bh[2];
#pragma unroll
        for (int jj=0; jj<2; jj++){
            float e0[8];
#pragma unroll
            for (int e=0; e<8; e++) e0[e] = elu_f(par[e] + pbr[jj][e]);
            f16x2 p0 = pk16(e0[0], e0[1]);
            f16x2 p1 = pk16(e0[2], e0[3]);
            f16x2 p2 = pk16(e0[4], e0[5]);
            f16x2 p3 = pk16(e0[6], e0[7]);
            f16x8 b = {p0[0],p0[1],p1[0],p1[1],p2[0],p2[1],p3[0],p3[1]};
            bh[jj] = b;
        }

        // ---- Layer 1: H1^T = W1^T @ H0^T (K=32)
        f32x4 acc[2][2];   // [mt=feat-tile][jj]
#pragma unroll
        for (int mt=0; mt<2; mt++)
#pragma unroll
        for (int jj=0; jj<2; jj++)
            acc[mt][jj] = __builtin_amdgcn_mfma_f32_16x16x32_f16(
                              wfr1[mt], bh[jj], b1v[mt], 0,0,0);

        // ---- elu + cvt: acc IS the 16x16x16 B-fragment (kc = mt)
        f16x4 bf[2][2];    // [jj][kc]
#pragma unroll
        for (int jj=0; jj<2; jj++)
#pragma unroll
        for (int kc=0; kc<2; kc++){
            f16x2 q0 = pk16(elu_f(acc[kc][jj][0]), elu_f(acc[kc][jj][1]));
            f16x2 q1 = pk16(elu_f(acc[kc][jj][2]), elu_f(acc[kc][jj][3]));
            f16x4 p = {q0[0],q0[1],q1[0],q1[1]};
            bf[jj][kc] = p;
        }

        // ---- Layer 2: O^T = W2^T @ H1^T (2 chained K=16 MFMAs) + store
        float* obase = out + ((size_t)(bnb*PP + ic*8 + i))*PP*OUTC;
#pragma unroll
        for (int jj=0; jj<2; jj++){
            int j = 32*w + 16*jj + ln;
#pragma unroll
            for (int mtO=0; mtO<2; mtO++){
                f32x4 c = b2v[mtO];
                c = __builtin_amdgcn_mfma_f32_16x16x16f16(w2t[mtO][0], bf[jj][0], c, 0,0,0);
                c = __builtin_amdgcn_mfma_f32_16x16x16f16(w2t[mtO][1], bf[jj][1], c, 0,0,0);
                f32x4 o;
#pragma unroll
                for (int q=0; q<4; q++) o[q] = elu_f(c[q]);
                *(f32x4*)(obase + (size_t)j*OUTC + 16*mtO + 4*h) = o;
            }
        }
        // no barrier, no loop LDS writes: stores drain asynchronously.
    }
}

extern "C" void kernel_launch(void* const* d_in, const int* in_sizes, int n_in,
                              void* d_out, int out_size, void* d_ws, size_t ws_size,
                              hipStream_t stream) {
    const float* x    = (const float*)d_in[0];
    const float* msk  = (const float*)d_in[1];
    const float* nw0  = (const float*)d_in[2];
    const float* nb0  = (const float*)d_in[3];
    const float* nw1  = (const float*)d_in[4];
    const float* nb1  = (const float*)d_in[5];
    const float* nw2  = (const float*)d_in[6];
    const float* nb2  = (const float*)d_in[7];
    const float* pw0  = (const float*)d_in[8];
    const float* pb0  = (const float*)d_in[9];
    const float* pw1  = (const float*)d_in[10];
    const float* pb1  = (const float*)d_in[11];
    const float* pw2  = (const float*)d_in[12];
    const float* pb2  = (const float*)d_in[13];
    float* out = (float*)d_out;

    float* pa = (float*)d_ws;                       // 8192*32 floats = 1 MiB
    float* pb = pa + (size_t)NROWS*HH;              // +1 MiB

    node_kernel<<<NROWS/256, 256, 0, stream>>>(x, msk, nw0, nb0, nw1, nb1,
                                               nw2, nb2, pw0, pb0, pa, pb);
    pair_kernel<<<BB*NBB*16, 256, 0, stream>>>(pa, pb, pw1, pb1,
                                               pw2, pb2, out);
}

// Round 14
// 65.429 us; speedup vs baseline: 1.0081x; 1.0050x over previous
//
#include <hip/hip_runtime.h>

// Problem dims (fixed by reference)
#define BB   2
#define NBB  32
#define PP   128
#define FF   32
#define HH   32
#define NO   8
#define OUTC 32
#define NROWS (BB*NBB*PP)   // 8192

typedef float    f32x4 __attribute__((ext_vector_type(4)));
typedef _Float16 f16x8 __attribute__((ext_vector_type(8)));
typedef _Float16 f16x4 __attribute__((ext_vector_type(4)));
typedef _Float16 f16x2 __attribute__((ext_vector_type(2)));

__device__ __forceinline__ float elu_f(float x){
    return x > 0.0f ? x : (__expf(x) - 1.0f);
}
// packed fp32x2 -> fp16x2 (RTZ), bit-cast to _Float16 vector type
__device__ __forceinline__ f16x2 pk16(float a, float b){
    return __builtin_bit_cast(f16x2, __builtin_amdgcn_cvt_pkrtz(a, b));
}

// Kernel A: node MLP + projection to pa/pb (pair_b0 folded into pa).
__global__ __launch_bounds__(256) void node_kernel(
    const float* __restrict__ x,  const float* __restrict__ msk,
    const float* __restrict__ w0, const float* __restrict__ b0,
    const float* __restrict__ w1, const float* __restrict__ b1,
    const float* __restrict__ w2, const float* __restrict__ b2,
    const float* __restrict__ pw0,const float* __restrict__ pb0,
    float* __restrict__ pa, float* __restrict__ pb)
{
    int row = blockIdx.x*256 + threadIdx.x;
    if (row >= NROWS) return;

    float xr[FF];
    const float4* xp = reinterpret_cast<const float4*>(x + (size_t)row*FF);
#pragma unroll
    for (int q=0;q<FF/4;q++){ float4 v=xp[q]; xr[4*q]=v.x; xr[4*q+1]=v.y; xr[4*q+2]=v.z; xr[4*q+3]=v.w; }

    float h[HH];
#pragma unroll
    for (int k=0;k<HH;k++) h[k]=b0[k];
#pragma unroll
    for (int m=0;m<FF;m++){
        float xm = xr[m];
#pragma unroll
        for (int k=0;k<HH;k++) h[k] += xm * w0[m*HH+k];
    }
#pragma unroll
    for (int k=0;k<HH;k++) h[k]=elu_f(h[k]);

    float g[HH];
#pragma unroll
    for (int k=0;k<HH;k++) g[k]=b1[k];
#pragma unroll
    for (int m=0;m<HH;m++){
        float hm=h[m];
#pragma unroll
        for (int k=0;k<HH;k++) g[k] += hm * w1[m*HH+k];
    }
#pragma unroll
    for (int k=0;k<HH;k++) g[k]=elu_f(g[k]);

    float mk = msk[row];
    float npj[NO];
#pragma unroll
    for (int k=0;k<NO;k++) npj[k]=b2[k];
#pragma unroll
    for (int m=0;m<HH;m++){
        float gm=g[m];
#pragma unroll
        for (int k=0;k<NO;k++) npj[k] += gm * w2[m*NO+k];
    }
#pragma unroll
    for (int k=0;k<NO;k++) npj[k]=elu_f(npj[k])*mk;

    float pav[HH], pbv[HH];
#pragma unroll
    for (int k=0;k<HH;k++){ pav[k]=pb0[k]; pbv[k]=0.0f; }
#pragma unroll
    for (int m=0;m<NO;m++){
        float nm=npj[m];
#pragma unroll
        for (int k=0;k<HH;k++){
            pav[k] += nm * pw0[m*HH+k];
            pbv[k] += nm * pw0[(NO+m)*HH+k];
        }
    }
    float4* pap = reinterpret_cast<float4*>(pa + (size_t)row*HH);
    float4* pbp = reinterpret_cast<float4*>(pb + (size_t)row*HH);
#pragma unroll
    for (int q=0;q<HH/4;q++){
        pap[q]=make_float4(pav[4*q],pav[4*q+1],pav[4*q+2],pav[4*q+3]);
        pbp[q]=make_float4(pbv[4*q],pbv[4*q+1],pbv[4*q+2],pbv[4*q+3]);
    }
}

// ---- Transposed-MFMA pair kernel, fp16, zero-LDS handoff, jj-split ----
// R13->R14: each wave owns ONE 16-j tile (jj split across 2x blocks, grid
// 1024->2048). Halves per-wave transient state (bh 8->4, acc 16->8, bf 8->4,
// pbr 16->8 VGPR => est ~90 total), halves per-block wall time (less skew),
// and __launch_bounds__(256,5) caps VGPR at 102 -> 5 waves/SIMD (vs 4) with
// no spill risk. Theory: the 66 us floor across R9-R13 is stall-dominated
// (real occupancy far below nominal, cf. R5's measured 16.5% vs 50%), so
// more+lighter waves is the remaining lever.
//   A frag (16x16x32): row m=ln(+16mt), k=8h+{0..7}
//   B frag: col=pair j, k=8h+{0..7};  D frag: col=pair j, feat 16mt+4h+{0..3}
//   L1 D-frag == 16x16x16 B-frag (kc=mt chain) -> zero-LDS layer handoff.
// Direct D-frag stores: full 64 B sectors, mtO halves back-to-back.
#define SM_SIZE 1024     // pas: 8 rows * 32 f32

__global__ __launch_bounds__(256, 5) void pair_kernel(
    const float* __restrict__ pa, const float* __restrict__ pb,
    const float* __restrict__ pw1, const float* __restrict__ pb1,
    const float* __restrict__ pw2, const float* __restrict__ pb2,
    float* __restrict__ out)
{
    __shared__ __align__(16) float pas[SM_SIZE/4];

    const int t   = threadIdx.x;
    const int l   = t & 63;
    const int w   = t >> 6;
    const int h   = l >> 4;
    const int ln  = l & 15;
    const int bnb = blockIdx.x >> 5;
    const int ic  = (blockIdx.x >> 1) & 15;
    const int p   = blockIdx.x & 1;
    const int jme = 64*p + 16*w + ln;      // this lane's pair row j

    // ---- stage pa rows for this block's 8 i's (pair_b0 folded)
    if (t < 64)
        ((f32x4*)pas)[t] = ((const f32x4*)(pa + ((size_t)bnb*PP + ic*8)*HH))[t];

    // ---- Layer-1 W1^T A-fragments (16x16x32: k=8h+{0..7})
    f16x8 wfr1[2];   // [mt]
#pragma unroll
    for (int mt=0; mt<2; mt++){
        f16x8 a;
#pragma unroll
        for (int e=0; e<8; e++)
            a[e] = (_Float16)pw1[(8*h+e)*32 + 16*mt + ln];   // W1^T[m][k]=W1[k][m]
        wfr1[mt] = a;
    }
    // ---- Layer-2 W2^T A-fragments (16x16x16: k=4h+{0..3}, chained kc)
    f16x4 w2t[2][2]; // [mtO][kc]
#pragma unroll
    for (int mtO=0; mtO<2; mtO++)
#pragma unroll
    for (int kc=0; kc<2; kc++){
        f16x4 a;
#pragma unroll
        for (int e=0; e<4; e++)
            a[e] = (_Float16)pw2[(16*kc + 4*h + e)*32 + 16*mtO + ln];
        w2t[mtO][kc] = a;
    }

    // ---- biases as D-fragment f32x4 (feature = 16mt+4h+q)
    f32x4 b1v[2], b2v[2];
#pragma unroll
    for (int mt=0; mt<2; mt++){
        b1v[mt] = *(const f32x4*)(pb1 + 16*mt + 4*h);
        b2v[mt] = *(const f32x4*)(pb2 + 16*mt + 4*h);
    }

    // ---- pb slice: this lane's B-frag k-slice for its single j
    float pbr[8];
    {
        const float* q = pb + ((size_t)bnb*PP + jme)*HH + 8*h;
        f32x4 v0 = *(const f32x4*)q, v1 = *(const f32x4*)(q+4);
#pragma unroll
        for (int c=0;c<4;c++){ pbr[c]=v0[c]; pbr[4+c]=v1[c]; }
    }
    __syncthreads();   // pas visible to all

    for (int i = 0; i < 8; i++){
        // ---- H0^T B-fragment straight into registers (fp16, packed cvt)
        float par[8];
        {
            const f32x4* pp = (const f32x4*)(pas + i*32 + 8*h);
            f32x4 v0 = pp[0], v1 = pp[1];
#pragma unroll
            for (int c=0;c<4;c++){ par[c]=v0[c]; par[4+c]=v1[c]; }
        }
        float e0[8];
#pragma unroll
        for (int e=0; e<8; e++) e0[e] = elu_f(par[e] + pbr[e]);
        f16x2 p0 = pk16(e0[0], e0[1]);
        f16x2 p1 = pk16(e0[2], e0[3]);
        f16x2 p2 = pk16(e0[4], e0[5]);
        f16x2 p3 = pk16(e0[6], e0[7]);
        f16x8 bh = {p0[0],p0[1],p1[0],p1[1],p2[0],p2[1],p3[0],p3[1]};

        // ---- Layer 1: H1^T = W1^T @ H0^T (K=32)
        f32x4 acc[2];   // [mt]
#pragma unroll
        for (int mt=0; mt<2; mt++)
            acc[mt] = __builtin_amdgcn_mfma_f32_16x16x32_f16(
                          wfr1[mt], bh, b1v[mt], 0,0,0);

        // ---- elu + cvt: acc IS the 16x16x16 B-fragment (kc = mt)
        f16x4 bf[2];    // [kc]
#pragma unroll
        for (int kc=0; kc<2; kc++){
            f16x2 q0 = pk16(elu_f(acc[kc][0]), elu_f(acc[kc][1]));
            f16x2 q1 = pk16(elu_f(acc[kc][2]), elu_f(acc[kc][3]));
            f16x4 pp = {q0[0],q0[1],q1[0],q1[1]};
            bf[kc] = pp;
        }

        // ---- Layer 2: O^T = W2^T @ H1^T (2 chained K=16 MFMAs) + store
        float* obase = out + ((size_t)(bnb*PP + ic*8 + i))*PP*OUTC;
#pragma unroll
        for (int mtO=0; mtO<2; mtO++){
            f32x4 c = b2v[mtO];
            c = __builtin_amdgcn_mfma_f32_16x16x16f16(w2t[mtO][0], bf[0], c, 0,0,0);
            c = __builtin_amdgcn_mfma_f32_16x16x16f16(w2t[mtO][1], bf[1], c, 0,0,0);
            f32x4 o;
#pragma unroll
            for (int q=0; q<4; q++) o[q] = elu_f(c[q]);
            *(f32x4*)(obase + (size_t)jme*OUTC + 16*mtO + 4*h) = o;
        }
        // no barrier, no loop LDS writes: stores drain asynchronously.
    }
}

extern "C" void kernel_launch(void* const* d_in, const int* in_sizes, int n_in,
                              void* d_out, int out_size, void* d_ws, size_t ws_size,
                              hipStream_t stream) {
    const float* x    = (const float*)d_in[0];
    const float* msk  = (const float*)d_in[1];
    const float* nw0  = (const float*)d_in[2];
    const float* nb0  = (const float*)d_in[3];
    const float* nw1  = (const float*)d_in[4];
    const float* nb1  = (const float*)d_in[5];
    const float* nw2  = (const float*)d_in[6];
    const float* nb2  = (const float*)d_in[7];
    const float* pw0  = (const float*)d_in[8];
    const float* pb0  = (const float*)d_in[9];
    const float* pw1  = (const float*)d_in[10];
    const float* pb1  = (const float*)d_in[11];
    const float* pw2  = (const float*)d_in[12];
    const float* pb2  = (const float*)d_in[13];
    float* out = (float*)d_out;

    float* pa = (float*)d_ws;                       // 8192*32 floats = 1 MiB
    float* pb = pa + (size_t)NROWS*HH;              // +1 MiB

    node_kernel<<<NROWS/256, 256, 0, stream>>>(x, msk, nw0, nb0, nw1, nb1,
                                               nw2, nb2, pw0, pb0, pa, pb);
    pair_kernel<<<BB*NBB*32, 256, 0, stream>>>(pa, pb, pw1, pb1,
                                               pw2, pb2, out);
}